// Round 1
// baseline (723.400 us; speedup 1.0000x reference)
//
#include <hip/hip_runtime.h>

// BiGRU, B=512, T=512, D=16, H=64.
// Key insight: backward direction only needs ONE cell step (ys_b[0] = GRUCell(x[:,T-1,:], 0)).
// Forward GRU: one wave per batch element; lane j owns hidden unit j and holds
// w_hh rows {j, H+j, 2H+j} in VGPRs (192 regs). h broadcast per step via LDS
// (same-address ds_read_b128 = conflict-free broadcast). x staged in 4KB LDS chunks.

#define Hh 64
#define Dd 16
#define Tt 512
#define Bb 512
#define CH 64   // timesteps per LDS x-chunk

__device__ __forceinline__ float sigmoid_fast(float v) {
    return 1.0f / (1.0f + __expf(-v));
}
__device__ __forceinline__ float tanh_fast(float v) {
    // tanh(v) = 1 - 2/(exp(2v)+1); saturates correctly at +/-inf
    float e = __expf(2.0f * v);
    return 1.0f - 2.0f / (e + 1.0f);
}

__global__ __launch_bounds__(64)
void bigru_fused_kernel(const float* __restrict__ x,
                        const float* __restrict__ w_ih_f, const float* __restrict__ w_hh_f,
                        const float* __restrict__ b_ih_f, const float* __restrict__ b_hh_f,
                        const float* __restrict__ w_ih_b, const float* __restrict__ w_hh_b,
                        const float* __restrict__ b_ih_b, const float* __restrict__ b_hh_b,
                        const float* __restrict__ fc_w,  const float* __restrict__ fc_b,
                        float* __restrict__ out)
{
    const int b = blockIdx.x;   // batch element
    const int j = threadIdx.x;  // hidden unit 0..63

    __shared__ __align__(16) float xbuf[CH * Dd];  // 4 KB: 64 timesteps of x[b,t,:]
    __shared__ __align__(16) float hbuf[2][Hh];    // double-buffered h

    // ---- preload recurrent weights into registers: rows j, H+j, 2H+j ----
    float wr[Hh], wz[Hh], wn[Hh];
    {
        const float4* r0 = (const float4*)(w_hh_f + (size_t)j * Hh);
        const float4* r1 = (const float4*)(w_hh_f + (size_t)(Hh + j) * Hh);
        const float4* r2 = (const float4*)(w_hh_f + (size_t)(2 * Hh + j) * Hh);
#pragma unroll
        for (int q = 0; q < Hh / 4; ++q) {
            float4 a = r0[q]; wr[4*q] = a.x; wr[4*q+1] = a.y; wr[4*q+2] = a.z; wr[4*q+3] = a.w;
            float4 c = r1[q]; wz[4*q] = c.x; wz[4*q+1] = c.y; wz[4*q+2] = c.z; wz[4*q+3] = c.w;
            float4 e = r2[q]; wn[4*q] = e.x; wn[4*q+1] = e.y; wn[4*q+2] = e.z; wn[4*q+3] = e.w;
        }
    }
    // input-projection weights: 3 rows x 16 = 12 float4
    float4 wir[4], wiz[4], win[4];
    {
        const float4* p0 = (const float4*)(w_ih_f + (size_t)j * Dd);
        const float4* p1 = (const float4*)(w_ih_f + (size_t)(Hh + j) * Dd);
        const float4* p2 = (const float4*)(w_ih_f + (size_t)(2 * Hh + j) * Dd);
#pragma unroll
        for (int q = 0; q < 4; ++q) { wir[q] = p0[q]; wiz[q] = p1[q]; win[q] = p2[q]; }
    }
    const float br  = b_ih_f[j]        + b_hh_f[j];
    const float bz  = b_ih_f[Hh + j]   + b_hh_f[Hh + j];
    const float bxn = b_ih_f[2*Hh + j];
    const float bhn = b_hh_f[2*Hh + j];

    float h = 0.0f;
    hbuf[0][j] = 0.0f;

    const float* xrow = x + (size_t)b * Tt * Dd;

    for (int tc = 0; tc < Tt / CH; ++tc) {
        __syncthreads();  // previous chunk's reads done (also covers hbuf init)
        {   // stage 64 timesteps (1024 floats) coalesced: 4 float4 per lane
            const float4* src = (const float4*)(xrow + (size_t)tc * CH * Dd);
            float4* dst = (float4*)xbuf;
#pragma unroll
            for (int q = 0; q < (CH * Dd / 4) / 64; ++q)
                dst[q * 64 + j] = src[q * 64 + j];
        }
        __syncthreads();

        for (int tt = 0; tt < CH; ++tt) {
            const int t   = tc * CH + tt;
            const int cur = t & 1;
            const int nxt = cur ^ 1;

            float a_r = br, a_z = bz, a_xn = bxn, a_hn = bhn;

            // ---- input projection: 3 gates x 16 dims ----
            const float4* x4 = (const float4*)(xbuf + tt * Dd);
#pragma unroll
            for (int q = 0; q < 4; ++q) {
                float4 xv = x4[q];
                a_r  += wir[q].x * xv.x + wir[q].y * xv.y + wir[q].z * xv.z + wir[q].w * xv.w;
                a_z  += wiz[q].x * xv.x + wiz[q].y * xv.y + wiz[q].z * xv.z + wiz[q].w * xv.w;
                a_xn += win[q].x * xv.x + win[q].y * xv.y + win[q].z * xv.z + win[q].w * xv.w;
            }

            // ---- recurrent matvec: h broadcast from LDS (b128 broadcast reads) ----
            const float4* h4 = (const float4*)(hbuf[cur]);
#pragma unroll
            for (int q = 0; q < Hh / 4; ++q) {
                float4 hv = h4[q];
                a_r  += wr[4*q]   * hv.x; a_z += wz[4*q]   * hv.x; a_hn += wn[4*q]   * hv.x;
                a_r  += wr[4*q+1] * hv.y; a_z += wz[4*q+1] * hv.y; a_hn += wn[4*q+1] * hv.y;
                a_r  += wr[4*q+2] * hv.z; a_z += wz[4*q+2] * hv.z; a_hn += wn[4*q+2] * hv.z;
                a_r  += wr[4*q+3] * hv.w; a_z += wz[4*q+3] * hv.w; a_hn += wn[4*q+3] * hv.w;
            }

            // ---- gates + state update ----
            float r = sigmoid_fast(a_r);
            float z = sigmoid_fast(a_z);
            float n = tanh_fast(a_xn + r * a_hn);
            h = n + z * (h - n);   // (1-z)*n + z*h

            hbuf[nxt][j] = h;
            __syncthreads();
        }
    }

    // ---- backward direction: single cell step from h=0 on x[:,T-1,:] ----
    // xbuf still holds last chunk; t=511 is at slot 63.
    float ar  = b_ih_b[j]        + b_hh_b[j];
    float az  = b_ih_b[Hh + j]   + b_hh_b[Hh + j];
    float axn = b_ih_b[2*Hh + j];
    float bhnb = b_hh_b[2*Hh + j];
    {
        const float4* xl = (const float4*)(xbuf + 63 * Dd);
        const float4* q0 = (const float4*)(w_ih_b + (size_t)j * Dd);
        const float4* q1 = (const float4*)(w_ih_b + (size_t)(Hh + j) * Dd);
        const float4* q2 = (const float4*)(w_ih_b + (size_t)(2 * Hh + j) * Dd);
#pragma unroll
        for (int q = 0; q < 4; ++q) {
            float4 xv = xl[q];
            float4 a = q0[q], c = q1[q], e = q2[q];
            ar  += a.x * xv.x + a.y * xv.y + a.z * xv.z + a.w * xv.w;
            az  += c.x * xv.x + c.y * xv.y + c.z * xv.z + c.w * xv.w;
            axn += e.x * xv.x + e.y * xv.y + e.z * xv.z + e.w * xv.w;
        }
    }
    float rb = sigmoid_fast(ar);
    float zb = sigmoid_fast(az);
    float nb = tanh_fast(axn + rb * bhnb);
    float hb = (1.0f - zb) * nb;   // h0 = 0

    // ---- fused FC: y[b] = fc_w[0:64].h_fwd + fc_w[64:128].h_bwd + fc_b ----
    float v = fc_w[j] * h + fc_w[Hh + j] * hb;
#pragma unroll
    for (int off = 32; off > 0; off >>= 1)
        v += __shfl_xor(v, off, 64);
    if (j == 0) out[b] = v + fc_b[0];
}

extern "C" void kernel_launch(void* const* d_in, const int* in_sizes, int n_in,
                              void* d_out, int out_size, void* d_ws, size_t ws_size,
                              hipStream_t stream) {
    const float* x      = (const float*)d_in[0];
    const float* w_ih_f = (const float*)d_in[1];
    const float* w_hh_f = (const float*)d_in[2];
    const float* b_ih_f = (const float*)d_in[3];
    const float* b_hh_f = (const float*)d_in[4];
    const float* w_ih_b = (const float*)d_in[5];
    const float* w_hh_b = (const float*)d_in[6];
    const float* b_ih_b = (const float*)d_in[7];
    const float* b_hh_b = (const float*)d_in[8];
    const float* fc_w   = (const float*)d_in[9];
    const float* fc_b   = (const float*)d_in[10];

    bigru_fused_kernel<<<dim3(Bb), dim3(64), 0, stream>>>(
        x, w_ih_f, w_hh_f, b_ih_f, b_hh_f,
        w_ih_b, w_hh_b, b_ih_b, b_hh_b, fc_w, fc_b,
        (float*)d_out);
}

// Round 2
// 649.665 us; speedup vs baseline: 1.1135x; 1.1135x over previous
//
#include <hip/hip_runtime.h>

// BiGRU, B=512, T=512, D=16, H=64.
// Backward direction needs only ONE cell step (ys_b[0] = GRUCell(x[:,T-1,:], 0)).
// Forward GRU: one wave per batch element; lane j owns hidden unit j and holds
// w_hh rows {j, H+j, 2H+j} in 192 VGPRs. h is broadcast per step via
// v_readlane (SGPR operand to FMA) -- no LDS, no barrier in the recurrence.
// Input projections xg are precomputed per 64-step chunk into LDS (gate-by-gate
// passes keep arch-VGPR demand ~215 < 256, avoiding AGPR spill traffic seen in
// round 1: VGPR_Count=156 + ~2x VALU instruction inflation).

#define Hh 64
#define Dd 16
#define Tt 512
#define Bb 512
#define CH 64   // timesteps per LDS chunk

__device__ __forceinline__ float sigmoid_fast(float v) {
    return 1.0f / (1.0f + __expf(-v));
}
__device__ __forceinline__ float tanh_fast(float v) {
    float e = __expf(2.0f * v);
    return 1.0f - 2.0f / (e + 1.0f);
}
__device__ __forceinline__ float lane_bcast(float v, int k) {
    return __int_as_float(__builtin_amdgcn_readlane(__float_as_int(v), k));
}

__global__ __launch_bounds__(64)
void bigru_fused_kernel(const float* __restrict__ x,
                        const float* __restrict__ w_ih_f, const float* __restrict__ w_hh_f,
                        const float* __restrict__ b_ih_f, const float* __restrict__ b_hh_f,
                        const float* __restrict__ w_ih_b, const float* __restrict__ w_hh_b,
                        const float* __restrict__ b_ih_b, const float* __restrict__ b_hh_b,
                        const float* __restrict__ fc_w,  const float* __restrict__ fc_b,
                        float* __restrict__ out)
{
    const int b = blockIdx.x;   // batch element
    const int j = threadIdx.x;  // hidden unit 0..63

    __shared__ __align__(16) float xbuf[CH * Dd];     // 4 KB raw x chunk
    __shared__ __align__(16) float xg[CH][3 * Hh];    // 48 KB precomputed input projections

    // ---- recurrent weights in registers: rows j, H+j, 2H+j of w_hh_f ----
    float wr[Hh], wz[Hh], wn[Hh];
    {
        const float4* r0 = (const float4*)(w_hh_f + (size_t)j * Hh);
        const float4* r1 = (const float4*)(w_hh_f + (size_t)(Hh + j) * Hh);
        const float4* r2 = (const float4*)(w_hh_f + (size_t)(2 * Hh + j) * Hh);
#pragma unroll
        for (int q = 0; q < Hh / 4; ++q) {
            float4 a = r0[q]; wr[4*q] = a.x; wr[4*q+1] = a.y; wr[4*q+2] = a.z; wr[4*q+3] = a.w;
            float4 c = r1[q]; wz[4*q] = c.x; wz[4*q+1] = c.y; wz[4*q+2] = c.z; wz[4*q+3] = c.w;
            float4 e = r2[q]; wn[4*q] = e.x; wn[4*q+1] = e.y; wn[4*q+2] = e.z; wn[4*q+3] = e.w;
        }
    }
    const float br  = b_ih_f[j]        + b_hh_f[j];
    const float bz  = b_ih_f[Hh + j]   + b_hh_f[Hh + j];
    const float bxn = b_ih_f[2*Hh + j];
    const float bhn = b_hh_f[2*Hh + j];

    float h = 0.0f;
    const float* xrow = x + (size_t)b * Tt * Dd;

    for (int tc = 0; tc < Tt / CH; ++tc) {
        __syncthreads();  // previous chunk's xg reads complete
        {   // stage 64 timesteps (1024 floats) coalesced: 4 float4 per lane
            const float4* src = (const float4*)(xrow + (size_t)tc * CH * Dd);
            float4* dst = (float4*)xbuf;
#pragma unroll
            for (int q = 0; q < (CH * Dd / 4) / 64; ++q)
                dst[q * 64 + j] = src[q * 64 + j];
        }
        __syncthreads();

        // ---- precompute input projections gate-by-gate (keeps only 16
        //      input-weight floats live at a time -> no AGPR spill) ----
#pragma unroll
        for (int g = 0; g < 3; ++g) {
            float4 wi[4];
            const float4* p = (const float4*)(w_ih_f + (size_t)(g * Hh + j) * Dd);
#pragma unroll
            for (int q = 0; q < 4; ++q) wi[q] = p[q];
            for (int tt = 0; tt < CH; ++tt) {
                const float4* x4 = (const float4*)(xbuf + tt * Dd);
                float acc = 0.0f;
#pragma unroll
                for (int q = 0; q < 4; ++q) {
                    float4 xv = x4[q];
                    acc += wi[q].x * xv.x + wi[q].y * xv.y + wi[q].z * xv.z + wi[q].w * xv.w;
                }
                xg[tt][g * Hh + j] = acc;
            }
        }
        __syncthreads();

        // ---- recurrence: h broadcast via readlane, zero LDS round-trips ----
        for (int tt = 0; tt < CH; ++tt) {
            float a_r  = br  + xg[tt][j];
            float a_z  = bz  + xg[tt][Hh + j];
            float a_xn = bxn + xg[tt][2 * Hh + j];
            float a_hn = bhn;
#pragma unroll
            for (int k = 0; k < Hh; ++k) {
                float hk = lane_bcast(h, k);
                a_r  += wr[k] * hk;
                a_z  += wz[k] * hk;
                a_hn += wn[k] * hk;
            }
            float r = sigmoid_fast(a_r);
            float z = sigmoid_fast(a_z);
            float n = tanh_fast(a_xn + r * a_hn);
            h = n + z * (h - n);   // (1-z)*n + z*h
        }
    }

    // ---- backward direction: single cell step from h=0 on x[:,T-1,:] ----
    // xbuf still holds the last chunk; t=511 is slot 63.
    float ar   = b_ih_b[j]        + b_hh_b[j];
    float az   = b_ih_b[Hh + j]   + b_hh_b[Hh + j];
    float axn  = b_ih_b[2*Hh + j];
    float bhnb = b_hh_b[2*Hh + j];
    {
        const float4* xl = (const float4*)(xbuf + 63 * Dd);
        const float4* q0 = (const float4*)(w_ih_b + (size_t)j * Dd);
        const float4* q1 = (const float4*)(w_ih_b + (size_t)(Hh + j) * Dd);
        const float4* q2 = (const float4*)(w_ih_b + (size_t)(2 * Hh + j) * Dd);
#pragma unroll
        for (int q = 0; q < 4; ++q) {
            float4 xv = xl[q];
            float4 a = q0[q], c = q1[q], e = q2[q];
            ar  += a.x * xv.x + a.y * xv.y + a.z * xv.z + a.w * xv.w;
            az  += c.x * xv.x + c.y * xv.y + c.z * xv.z + c.w * xv.w;
            axn += e.x * xv.x + e.y * xv.y + e.z * xv.z + e.w * xv.w;
        }
    }
    float rb = sigmoid_fast(ar);
    float zb = sigmoid_fast(az);
    float nb = tanh_fast(axn + rb * bhnb);
    float hb = (1.0f - zb) * nb;   // h0 = 0

    // ---- fused FC: y[b] = fc_w[0:64].h_fwd + fc_w[64:128].h_bwd + fc_b ----
    float v = fc_w[j] * h + fc_w[Hh + j] * hb;
#pragma unroll
    for (int off = 32; off > 0; off >>= 1)
        v += __shfl_xor(v, off, 64);
    if (j == 0) out[b] = v + fc_b[0];
}

extern "C" void kernel_launch(void* const* d_in, const int* in_sizes, int n_in,
                              void* d_out, int out_size, void* d_ws, size_t ws_size,
                              hipStream_t stream) {
    const float* x      = (const float*)d_in[0];
    const float* w_ih_f = (const float*)d_in[1];
    const float* w_hh_f = (const float*)d_in[2];
    const float* b_ih_f = (const float*)d_in[3];
    const float* b_hh_f = (const float*)d_in[4];
    const float* w_ih_b = (const float*)d_in[5];
    const float* w_hh_b = (const float*)d_in[6];
    const float* b_ih_b = (const float*)d_in[7];
    const float* b_hh_b = (const float*)d_in[8];
    const float* fc_w   = (const float*)d_in[9];
    const float* fc_b   = (const float*)d_in[10];

    bigru_fused_kernel<<<dim3(Bb), dim3(64), 0, stream>>>(
        x, w_ih_f, w_hh_f, b_ih_f, b_hh_f,
        w_ih_b, w_hh_b, b_ih_b, b_hh_b, fc_w, fc_b,
        (float*)d_out);
}

// Round 3
// 595.584 us; speedup vs baseline: 1.2146x; 1.0908x over previous
//
#include <hip/hip_runtime.h>

// BiGRU, B=512, T=512, D=16, H=64.
// Backward direction needs only ONE cell step (ys_b[0] = GRUCell(x[:,T-1,:], 0)).
// Forward GRU: one wave per batch element; lane j owns hidden unit j and holds
// w_hh rows {j, H+j, 2H+j} in 192 VGPRs. h broadcast per step via v_readlane.
// Round-2 lesson: without an occupancy directive the allocator capped arch
// VGPRs at 184 and AGPR-spilled the weight arrays -> ~800 VALU instr/step
// (one v_accvgpr_read per weight use). Fix: __launch_bounds__(64,1) (1 wave/EU
// -> full 512-reg unified file usable; grid = 2 waves/CU regardless) + bias
// folding into xg to trim live floats.

#define Hh 64
#define Dd 16
#define Tt 512
#define Bb 512
#define CH 64   // timesteps per LDS chunk

__device__ __forceinline__ float sigmoid_fast(float v) {
    return 1.0f / (1.0f + __expf(-v));
}
__device__ __forceinline__ float tanh_fast(float v) {
    float e = __expf(2.0f * v);
    return 1.0f - 2.0f / (e + 1.0f);
}
__device__ __forceinline__ float lane_bcast(float v, int k) {
    return __int_as_float(__builtin_amdgcn_readlane(__float_as_int(v), k));
}

__global__ __launch_bounds__(64, 1)
void bigru_fused_kernel(const float* __restrict__ x,
                        const float* __restrict__ w_ih_f, const float* __restrict__ w_hh_f,
                        const float* __restrict__ b_ih_f, const float* __restrict__ b_hh_f,
                        const float* __restrict__ w_ih_b, const float* __restrict__ w_hh_b,
                        const float* __restrict__ b_ih_b, const float* __restrict__ b_hh_b,
                        const float* __restrict__ fc_w,  const float* __restrict__ fc_b,
                        float* __restrict__ out)
{
    const int b = blockIdx.x;   // batch element
    const int j = threadIdx.x;  // hidden unit 0..63

    __shared__ __align__(16) float xbuf[CH * Dd];      // 4 KB raw x chunk
    __shared__ __align__(16) float xg[3][CH * Hh];     // 48 KB input projections (+bias)

    // ---- recurrent weights in registers: rows j, H+j, 2H+j of w_hh_f ----
    float wr[Hh], wz[Hh], wn[Hh];
    {
        const float4* r0 = (const float4*)(w_hh_f + (size_t)j * Hh);
        const float4* r1 = (const float4*)(w_hh_f + (size_t)(Hh + j) * Hh);
        const float4* r2 = (const float4*)(w_hh_f + (size_t)(2 * Hh + j) * Hh);
#pragma unroll
        for (int q = 0; q < Hh / 4; ++q) {
            float4 a = r0[q]; wr[4*q] = a.x; wr[4*q+1] = a.y; wr[4*q+2] = a.z; wr[4*q+3] = a.w;
            float4 c = r1[q]; wz[4*q] = c.x; wz[4*q+1] = c.y; wz[4*q+2] = c.z; wz[4*q+3] = c.w;
            float4 e = r2[q]; wn[4*q] = e.x; wn[4*q+1] = e.y; wn[4*q+2] = e.z; wn[4*q+3] = e.w;
        }
    }
    // only bhn must stay separate (it multiplies with r before tanh);
    // all other biases are folded into xg during precompute.
    const float bhn = b_hh_f[2 * Hh + j];

    float h = 0.0f;
    const float* xrow = x + (size_t)b * Tt * Dd;

    for (int tc = 0; tc < Tt / CH; ++tc) {
        __syncthreads();  // previous chunk's xg reads complete
        {   // stage 64 timesteps (1024 floats) coalesced: 4 float4 per lane
            const float4* src = (const float4*)(xrow + (size_t)tc * CH * Dd);
            float4* dst = (float4*)xbuf;
#pragma unroll
            for (int q = 0; q < (CH * Dd / 4) / 64; ++q)
                dst[q * 64 + j] = src[q * 64 + j];
        }
        __syncthreads();

        // ---- input projections gate-by-gate, biases folded in ----
#pragma unroll
        for (int g = 0; g < 3; ++g) {
            float4 wi[4];
            const float4* p = (const float4*)(w_ih_f + (size_t)(g * Hh + j) * Dd);
#pragma unroll
            for (int q = 0; q < 4; ++q) wi[q] = p[q];
            const float bias = (g == 2) ? b_ih_f[2 * Hh + j]
                                        : (b_ih_f[g * Hh + j] + b_hh_f[g * Hh + j]);
            for (int tt = 0; tt < CH; ++tt) {
                const float4* x4 = (const float4*)(xbuf + tt * Dd);
                float acc = bias;
#pragma unroll
                for (int q = 0; q < 4; ++q) {
                    float4 xv = x4[q];
                    acc += wi[q].x * xv.x + wi[q].y * xv.y + wi[q].z * xv.z + wi[q].w * xv.w;
                }
                xg[g][tt * Hh + j] = acc;
            }
        }
        __syncthreads();

        // ---- recurrence: h broadcast via readlane; unroll 2 to pipeline
        //      the xg LDS reads against the previous step's FMA stream ----
#pragma unroll 2
        for (int tt = 0; tt < CH; ++tt) {
            float a_r  = xg[0][tt * Hh + j];
            float a_z  = xg[1][tt * Hh + j];
            float a_xn = xg[2][tt * Hh + j];
            float a_hn = bhn;
#pragma unroll
            for (int k = 0; k < Hh; ++k) {
                float hk = lane_bcast(h, k);
                a_r  += wr[k] * hk;
                a_z  += wz[k] * hk;
                a_hn += wn[k] * hk;
            }
            float r = sigmoid_fast(a_r);
            float z = sigmoid_fast(a_z);
            float n = tanh_fast(a_xn + r * a_hn);
            h = n + z * (h - n);   // (1-z)*n + z*h
        }
    }

    // ---- backward direction: single cell step from h=0 on x[:,T-1,:] ----
    // xbuf still holds the last chunk; t=511 is slot 63.
    float ar   = b_ih_b[j]        + b_hh_b[j];
    float az   = b_ih_b[Hh + j]   + b_hh_b[Hh + j];
    float axn  = b_ih_b[2*Hh + j];
    float bhnb = b_hh_b[2*Hh + j];
    {
        const float4* xl = (const float4*)(xbuf + 63 * Dd);
        const float4* q0 = (const float4*)(w_ih_b + (size_t)j * Dd);
        const float4* q1 = (const float4*)(w_ih_b + (size_t)(Hh + j) * Dd);
        const float4* q2 = (const float4*)(w_ih_b + (size_t)(2 * Hh + j) * Dd);
#pragma unroll
        for (int q = 0; q < 4; ++q) {
            float4 xv = xl[q];
            float4 a = q0[q], c = q1[q], e = q2[q];
            ar  += a.x * xv.x + a.y * xv.y + a.z * xv.z + a.w * xv.w;
            az  += c.x * xv.x + c.y * xv.y + c.z * xv.z + c.w * xv.w;
            axn += e.x * xv.x + e.y * xv.y + e.z * xv.z + e.w * xv.w;
        }
    }
    float rb = sigmoid_fast(ar);
    float zb = sigmoid_fast(az);
    float nb = tanh_fast(axn + rb * bhnb);
    float hb = (1.0f - zb) * nb;   // h0 = 0

    // ---- fused FC: y[b] = fc_w[0:64].h_fwd + fc_w[64:128].h_bwd + fc_b ----
    float v = fc_w[j] * h + fc_w[Hh + j] * hb;
#pragma unroll
    for (int off = 32; off > 0; off >>= 1)
        v += __shfl_xor(v, off, 64);
    if (j == 0) out[b] = v + fc_b[0];
}

extern "C" void kernel_launch(void* const* d_in, const int* in_sizes, int n_in,
                              void* d_out, int out_size, void* d_ws, size_t ws_size,
                              hipStream_t stream) {
    const float* x      = (const float*)d_in[0];
    const float* w_ih_f = (const float*)d_in[1];
    const float* w_hh_f = (const float*)d_in[2];
    const float* b_ih_f = (const float*)d_in[3];
    const float* b_hh_f = (const float*)d_in[4];
    const float* w_ih_b = (const float*)d_in[5];
    const float* w_hh_b = (const float*)d_in[6];
    const float* b_ih_b = (const float*)d_in[7];
    const float* b_hh_b = (const float*)d_in[8];
    const float* fc_w   = (const float*)d_in[9];
    const float* fc_b   = (const float*)d_in[10];

    bigru_fused_kernel<<<dim3(Bb), dim3(64), 0, stream>>>(
        x, w_ih_f, w_hh_f, b_ih_f, b_hh_f,
        w_ih_b, w_hh_b, b_ih_b, b_hh_b, fc_w, fc_b,
        (float*)d_out);
}

// Round 4
// 420.145 us; speedup vs baseline: 1.7218x; 1.4176x over previous
//
#include <hip/hip_runtime.h>

// BiGRU, B=512, T=512, D=16, H=64.
// Backward direction needs only ONE cell step (ys_b[0] = GRUCell(x[:,T-1,:], 0)).
//
// Round-3 lesson: single-wave-per-batch needs 192 live weight floats -> the
// allocator pins arch VGPRs at 192 and manufactures AGPR copy traffic
// (~790 instr/step observed vs ~275 needed), and only 2/4 SIMDs per CU work.
//
// This version: 4 waves per batch (block=256), K-split recurrent matvec.
//  - wave w holds cols [16w,16w+16) of w_hh rows {j,64+j,128+j}: 48 VGPRs.
//  - per step: 16 readlanes (h replicated per wave) + 48 FMAs -> 3 LDS
//    partials -> ONE barrier (parity double-buffer) -> all waves reduce
//    (15 conflict-free ds_read_b32) + compute gates redundantly -> identical
//    h in every wave (same add order => bitwise equal).
//  - 512 blocks x 4 waves = 8 waves/CU = 2/SIMD: all SIMDs busy, co-resident
//    block hides barrier/LDS latency.

#define Hh 64
#define Dd 16
#define Tt 512
#define Bb 512
#define CH 64   // timesteps per LDS chunk
#define NW 4    // waves per block
#define KW 16   // k-columns per wave

__device__ __forceinline__ float sigmoid_fast(float v) {
    return 1.0f / (1.0f + __expf(-v));
}
__device__ __forceinline__ float tanh_fast(float v) {
    float e = __expf(2.0f * v);
    return 1.0f - 2.0f / (e + 1.0f);
}
__device__ __forceinline__ float lane_bcast(float v, int k) {
    return __int_as_float(__builtin_amdgcn_readlane(__float_as_int(v), k));
}
__device__ __forceinline__ float dot4(float4 a, float4 b) {
    return a.x * b.x + a.y * b.y + a.z * b.z + a.w * b.w;
}

__global__ __launch_bounds__(256, 2)
void bigru_fused_kernel(const float* __restrict__ x,
                        const float* __restrict__ w_ih_f, const float* __restrict__ w_hh_f,
                        const float* __restrict__ b_ih_f, const float* __restrict__ b_hh_f,
                        const float* __restrict__ w_ih_b, const float* __restrict__ w_hh_b,
                        const float* __restrict__ b_ih_b, const float* __restrict__ b_hh_b,
                        const float* __restrict__ fc_w,  const float* __restrict__ fc_b,
                        float* __restrict__ out)
{
    const int tid = threadIdx.x;
    const int j   = tid & 63;            // hidden unit
    const int w   = tid >> 6;            // wave id 0..3
    const int b   = blockIdx.x;          // batch element
    const int k0  = __builtin_amdgcn_readfirstlane(w << 4);  // SGPR k-base

    __shared__ __align__(16) float xbuf[CH * Dd];        // 4 KB raw x chunk
    __shared__ __align__(16) float xg[3][CH][Hh];        // 48 KB input proj (+bias)
    __shared__ __align__(16) float parts[2][NW][3][Hh];  // 6 KB matvec partials

    // ---- recurrent weights: rows {j,64+j,128+j}, cols [k0,k0+16) -> 48 regs ----
    float wr[KW], wz[KW], wn[KW];
    {
        const float4* r0 = (const float4*)(w_hh_f + (size_t)j            * Hh + k0);
        const float4* r1 = (const float4*)(w_hh_f + (size_t)(Hh + j)     * Hh + k0);
        const float4* r2 = (const float4*)(w_hh_f + (size_t)(2 * Hh + j) * Hh + k0);
#pragma unroll
        for (int q = 0; q < KW / 4; ++q) {
            float4 a = r0[q]; wr[4*q] = a.x; wr[4*q+1] = a.y; wr[4*q+2] = a.z; wr[4*q+3] = a.w;
            float4 c = r1[q]; wz[4*q] = c.x; wz[4*q+1] = c.y; wz[4*q+2] = c.z; wz[4*q+3] = c.w;
            float4 e = r2[q]; wn[4*q] = e.x; wn[4*q+1] = e.y; wn[4*q+2] = e.z; wn[4*q+3] = e.w;
        }
    }
    // ---- input-projection weights (hoisted; 48 regs) + biases ----
    float4 wir[4], wiz[4], win[4];
    {
        const float4* p0 = (const float4*)(w_ih_f + (size_t)j            * Dd);
        const float4* p1 = (const float4*)(w_ih_f + (size_t)(Hh + j)     * Dd);
        const float4* p2 = (const float4*)(w_ih_f + (size_t)(2 * Hh + j) * Dd);
#pragma unroll
        for (int q = 0; q < 4; ++q) { wir[q] = p0[q]; wiz[q] = p1[q]; win[q] = p2[q]; }
    }
    const float bxr = b_ih_f[j]          + b_hh_f[j];
    const float bxz = b_ih_f[Hh + j]     + b_hh_f[Hh + j];
    const float bxn = b_ih_f[2 * Hh + j];
    const float bhn = b_hh_f[2 * Hh + j];

    float h = 0.0f;
    const float* xrow = x + (size_t)b * Tt * Dd;

    for (int tc = 0; tc < Tt / CH; ++tc) {
        __syncthreads();  // previous chunk fully consumed
        // stage 64 timesteps (1024 floats): one float4 per thread, coalesced
        ((float4*)xbuf)[tid] = ((const float4*)(xrow + (size_t)tc * CH * Dd))[tid];
        __syncthreads();

        // ---- input projections: wave w covers tt in [16w, 16w+16) ----
#pragma unroll 4
        for (int tt2 = 0; tt2 < KW; ++tt2) {
            const int tt = (w << 4) + tt2;
            const float4* x4 = (const float4*)(xbuf + tt * Dd);
            float4 xv0 = x4[0], xv1 = x4[1], xv2 = x4[2], xv3 = x4[3];
            float ar = bxr + dot4(wir[0], xv0) + dot4(wir[1], xv1) + dot4(wir[2], xv2) + dot4(wir[3], xv3);
            float az = bxz + dot4(wiz[0], xv0) + dot4(wiz[1], xv1) + dot4(wiz[2], xv2) + dot4(wiz[3], xv3);
            float an = bxn + dot4(win[0], xv0) + dot4(win[1], xv1) + dot4(win[2], xv2) + dot4(win[3], xv3);
            xg[0][tt][j] = ar;
            xg[1][tt][j] = az;
            xg[2][tt][j] = an;
        }
        __syncthreads();

        // ---- recurrence: K-split matvec + one barrier per step ----
        for (int tt = 0; tt < CH; ++tt) {
            const int cur = tt & 1;
            float pr = 0.0f, pz = 0.0f, pn = 0.0f;
#pragma unroll
            for (int kk = 0; kk < KW; ++kk) {
                float hk = lane_bcast(h, k0 + kk);
                pr += wr[kk] * hk;
                pz += wz[kk] * hk;
                pn += wn[kk] * hk;
            }
            parts[cur][w][0][j] = pr;
            parts[cur][w][1][j] = pz;
            parts[cur][w][2][j] = pn;
            __syncthreads();

            float ar = xg[0][tt][j];
            float az = xg[1][tt][j];
            float xn = xg[2][tt][j];
            float an = bhn;
#pragma unroll
            for (int w2 = 0; w2 < NW; ++w2) {
                ar += parts[cur][w2][0][j];
                az += parts[cur][w2][1][j];
                an += parts[cur][w2][2][j];
            }
            float r = sigmoid_fast(ar);
            float z = sigmoid_fast(az);
            float n = tanh_fast(xn + r * an);
            h = n + z * (h - n);   // (1-z)*n + z*h  -- identical in all waves
        }
    }

    // ---- tail: backward single cell step + FC, wave 0 only ----
    if (w == 0) {
        float ar   = b_ih_b[j]          + b_hh_b[j];
        float az   = b_ih_b[Hh + j]     + b_hh_b[Hh + j];
        float axn  = b_ih_b[2 * Hh + j];
        float bhnb = b_hh_b[2 * Hh + j];
        {
            const float4* xl = (const float4*)(xbuf + 63 * Dd);  // t = 511
            const float4* q0 = (const float4*)(w_ih_b + (size_t)j            * Dd);
            const float4* q1 = (const float4*)(w_ih_b + (size_t)(Hh + j)     * Dd);
            const float4* q2 = (const float4*)(w_ih_b + (size_t)(2 * Hh + j) * Dd);
#pragma unroll
            for (int q = 0; q < 4; ++q) {
                float4 xv = xl[q];
                float4 a = q0[q], c = q1[q], e = q2[q];
                ar  += a.x * xv.x + a.y * xv.y + a.z * xv.z + a.w * xv.w;
                az  += c.x * xv.x + c.y * xv.y + c.z * xv.z + c.w * xv.w;
                axn += e.x * xv.x + e.y * xv.y + e.z * xv.z + e.w * xv.w;
            }
        }
        float rb = sigmoid_fast(ar);
        float zb = sigmoid_fast(az);
        float nb = tanh_fast(axn + rb * bhnb);
        float hb = (1.0f - zb) * nb;   // h0 = 0

        float v = fc_w[j] * h + fc_w[Hh + j] * hb;
#pragma unroll
        for (int off = 32; off > 0; off >>= 1)
            v += __shfl_xor(v, off, 64);
        if (j == 0) out[b] = v + fc_b[0];
    }
}

extern "C" void kernel_launch(void* const* d_in, const int* in_sizes, int n_in,
                              void* d_out, int out_size, void* d_ws, size_t ws_size,
                              hipStream_t stream) {
    const float* x      = (const float*)d_in[0];
    const float* w_ih_f = (const float*)d_in[1];
    const float* w_hh_f = (const float*)d_in[2];
    const float* b_ih_f = (const float*)d_in[3];
    const float* b_hh_f = (const float*)d_in[4];
    const float* w_ih_b = (const float*)d_in[5];
    const float* w_hh_b = (const float*)d_in[6];
    const float* b_ih_b = (const float*)d_in[7];
    const float* b_hh_b = (const float*)d_in[8];
    const float* fc_w   = (const float*)d_in[9];
    const float* fc_b   = (const float*)d_in[10];

    bigru_fused_kernel<<<dim3(Bb), dim3(NW * 64), 0, stream>>>(
        x, w_ih_f, w_hh_f, b_ih_f, b_hh_f,
        w_ih_b, w_hh_b, b_ih_b, b_hh_b, fc_w, fc_b,
        (float*)d_out);
}